// Round 6
// baseline (959.256 us; speedup 1.0000x reference)
//
#include <hip/hip_runtime.h>
#include <hip/hip_bf16.h>

typedef unsigned short u16;
typedef unsigned int u32;
typedef __attribute__((ext_vector_type(8))) short short8;
typedef __attribute__((ext_vector_type(4))) float f32x4;

#define B_ 4
#define T_ 2048
#define D_ 1024
#define H_ 16
#define HS_ 64
#define BT (B_*T_)

__device__ __forceinline__ float bf2f(u16 b){ union{u32 u; float f;} v; v.u=((u32)b)<<16; return v.f; }
__device__ __forceinline__ u16 f2bf(float f){
    __hip_bfloat16 h = __float2bfloat16(f);
    union{__hip_bfloat16 h; u16 u;} v; v.h = h; return v.u;
}
// split f32 into hi/lo bf16: x ~= hi + lo
__device__ __forceinline__ void split2(float x, u16& h, u16& l){
    u16 hb = f2bf(x);
    float fh = bf2f(hb);
    h = hb; l = f2bf(x - fh);
}
union U4 { u16 s[4]; uint2 v; };
union S8 { u16 s[8]; short8 v; };

// async global->LDS, 16B per lane; LDS dest wave-linear (base + lane*16)
#define GLD16(g,l) __builtin_amdgcn_global_load_lds( \
    (__attribute__((address_space(1))) void*)(u16*)(g), \
    (__attribute__((address_space(3))) void*)(l), 16, 0, 0)

// XOR-swizzled offset into a row-major [R][64]-u16 LDS tile, 16B-chunk granularity.
// Element (row, col): chunk c = col>>3 placed at c^(row&7). Readers/writers must agree.
// Verified conflict-free in round 5 (SQ_LDS_BANK_CONFLICT == 0).
__device__ __forceinline__ int swz(int row, int col){
    return row*64 + (((col>>3) ^ (row&7))<<3) + (col&7);
}

// ---- pack: Wt[n][d] (split hi/lo) = W_z[h][d][e], n = z*1024 + h*64 + e ----
__global__ __launch_bounds__(256) void pack_w(const float* __restrict__ Wq,
                                              const float* __restrict__ Wk,
                                              const float* __restrict__ Wv,
                                              u16* __restrict__ Wth,
                                              u16* __restrict__ Wtl)
{
    __shared__ float Tl[64*68];
    const int h = blockIdx.x, dt = blockIdx.y, z = blockIdx.z;
    const float* src = (z==0) ? Wq : ((z==1) ? Wk : Wv);
    const int t = threadIdx.x;
    const int d0 = dt*64;
    #pragma unroll
    for (int i=0;i<4;++i){
        int ci = t + 256*i;
        int dr = ci>>4, ec = ci&15;
        float4 v = *(const float4*)(src + ((size_t)h*D_ + d0+dr)*HS_ + ec*4);
        *(float4*)(Tl + dr*68 + ec*4) = v;
    }
    __syncthreads();
    #pragma unroll
    for (int i=0;i<4;++i){
        int ci = t + 256*i;
        int e = ci>>4, dc = ci&15;
        U4 hh, ll;
        #pragma unroll
        for (int j=0;j<4;++j){
            float f = Tl[(dc*4+j)*68 + e];
            split2(f, hh.s[j], ll.s[j]);
        }
        int n = z*D_ + h*HS_ + e;
        *(uint2*)(Wth + (size_t)n*D_ + d0 + dc*4) = hh.v;
        *(uint2*)(Wtl + (size_t)n*D_ + d0 + dc*4) = ll.v;
    }
}

// ---- QKV GEMM: qkv[t][col] = x[t][:]·Wt[col][:], col in [0,3072) ----
__global__ __launch_bounds__(256) void gemm_qkv(const float* __restrict__ x,
                                                const u16* __restrict__ Wth,
                                                const u16* __restrict__ Wtl,
                                                float* __restrict__ qo,
                                                u16* __restrict__ kho, u16* __restrict__ klo,
                                                u16* __restrict__ vth, u16* __restrict__ vtl)
{
    __shared__ u16 Ash[128*32], Asl[128*32];
    __shared__ u16 Bsh[128*32], Bsl[128*32];
    const int n0 = blockIdx.x*128, m0 = blockIdx.y*128;
    const int t = threadIdx.x;
    const int w = t>>6, lane = t&63, quad = lane>>4, l16 = lane&15;
    const int wm = (w>>1)*64, wn = (w&1)*64;
    f32x4 acc[4][4];
    #pragma unroll
    for (int i=0;i<4;++i)
        #pragma unroll
        for (int j=0;j<4;++j) acc[i][j] = (f32x4){0.f,0.f,0.f,0.f};
    for (int kt=0; kt<32; ++kt){
        const int k0 = kt*32;
        #pragma unroll
        for (int i=0;i<2;++i){           // B: async 16B chunks, wave-linear LDS dest
            int ci = t + 256*i;
            int row = ci>>2, c = ci&3;
            GLD16(Wth + (size_t)(n0+row)*D_ + k0 + c*8, Bsh + ci*8);
            GLD16(Wtl + (size_t)(n0+row)*D_ + k0 + c*8, Bsl + ci*8);
        }
        #pragma unroll
        for (int i=0;i<4;++i){           // A: f32 load + split
            int ci = t + 256*i;
            int row = ci>>3, c4 = ci&7;
            float4 av = *(const float4*)(x + (size_t)(m0+row)*D_ + k0 + c4*4);
            U4 hh, ll;
            split2(av.x, hh.s[0], ll.s[0]); split2(av.y, hh.s[1], ll.s[1]);
            split2(av.z, hh.s[2], ll.s[2]); split2(av.w, hh.s[3], ll.s[3]);
            *(uint2*)(Ash + row*32 + c4*4) = hh.v;
            *(uint2*)(Asl + row*32 + c4*4) = ll.v;
        }
        __syncthreads();
        short8 afh[4], afl[4], bfh[4], bfl[4];
        #pragma unroll
        for (int mi=0;mi<4;++mi){
            afh[mi] = *(const short8*)(Ash + (wm+mi*16+l16)*32 + quad*8);
            afl[mi] = *(const short8*)(Asl + (wm+mi*16+l16)*32 + quad*8);
        }
        #pragma unroll
        for (int ni=0;ni<4;++ni){
            bfh[ni] = *(const short8*)(Bsh + (wn+ni*16+l16)*32 + quad*8);
            bfl[ni] = *(const short8*)(Bsl + (wn+ni*16+l16)*32 + quad*8);
        }
        #pragma unroll
        for (int mi=0;mi<4;++mi)
            #pragma unroll
            for (int ni=0;ni<4;++ni){
                acc[mi][ni] = __builtin_amdgcn_mfma_f32_16x16x32_bf16(afh[mi], bfh[ni], acc[mi][ni], 0,0,0);
                acc[mi][ni] = __builtin_amdgcn_mfma_f32_16x16x32_bf16(afh[mi], bfl[ni], acc[mi][ni], 0,0,0);
                acc[mi][ni] = __builtin_amdgcn_mfma_f32_16x16x32_bf16(afl[mi], bfh[ni], acc[mi][ni], 0,0,0);
            }
        __syncthreads();
    }
    const int z = n0 >> 10;              // block-uniform (128 | 1024)
    if (z == 0){
        #pragma unroll
        for (int ni=0;ni<4;++ni){
            const int nloc = (n0 & 1023) + wn + ni*16 + l16;
            #pragma unroll
            for (int mi=0;mi<4;++mi){
                const int row = m0 + wm + mi*16 + quad*4;
                #pragma unroll
                for (int r=0;r<4;++r)
                    qo[(size_t)(row+r)*D_ + nloc] = acc[mi][ni][r];
            }
        }
    } else if (z == 1){
        #pragma unroll
        for (int ni=0;ni<4;++ni){
            const int nloc = (n0 & 1023) + wn + ni*16 + l16;
            #pragma unroll
            for (int mi=0;mi<4;++mi){
                const int row = m0 + wm + mi*16 + quad*4;
                #pragma unroll
                for (int r=0;r<4;++r){
                    u16 hh, ll; split2(acc[mi][ni][r], hh, ll);
                    kho[(size_t)(row+r)*D_ + nloc] = hh;
                    klo[(size_t)(row+r)*D_ + nloc] = ll;
                }
            }
        }
    } else {
        #pragma unroll
        for (int ni=0;ni<4;++ni){
            const int nloc = (n0 & 1023) + wn + ni*16 + l16;
            const int hloc = nloc>>6, e = nloc&63;
            #pragma unroll
            for (int mi=0;mi<4;++mi){
                const int rowb = m0 + wm + mi*16 + quad*4;   // multiple of 4
                const int bidx = rowb >> 11, tloc = rowb & 2047;
                U4 hh, ll;
                #pragma unroll
                for (int r=0;r<4;++r) split2(acc[mi][ni][r], hh.s[r], ll.s[r]);
                const size_t adr = ((size_t)((bidx*16 + hloc)*64 + e))*T_ + tloc;
                *(uint2*)(vth + adr) = hh.v;
                *(uint2*)(vtl + adr) = ll.v;
            }
        }
    }
}

// ---- causal flash attention; q-tile 128, 4 waves x 32 q-rows, pre-split K/V ----
// LDS 48KB -> 3 blocks/CU. P round-trip is per-wave, barrier-free (same-wave
// LDS ops complete in order; asm memory clobber pins compiler ordering).
__global__ __launch_bounds__(256,3) void attn(const float* __restrict__ q,
                                            const u16* __restrict__ kh, const u16* __restrict__ kl,
                                            const u16* __restrict__ vth, const u16* __restrict__ vtl,
                                            float* __restrict__ att)
{
    __shared__ u16 Ksh[64*64], Ksl[64*64];   // [kv][e], swizzled (16 KB)
    __shared__ u16 Vsh[64*64], Vsl[64*64];   // [e][kv], swizzled (16 KB)
    __shared__ u16 Ph[4*16*64], Pl[4*16*64]; // per-wave [16][64], phased per M-tile (16 KB)
    const int qi = blockIdx.x;               // q-tile of 128
    const int bh = blockIdx.y;
    const int b = bh >> 4, h = bh & 15;
    const int t = threadIdx.x;
    const int w = t>>6, lane = t&63, quad = lane>>4, l16 = lane&15;
    const int qrow = qi*128 + w*32;          // wave's absolute q base (32 rows)

    short8 qh_[2][2], ql_[2][2];             // [mi][ks]
    #pragma unroll
    for (int mi=0;mi<2;++mi){
        const float* qp = q + ((size_t)(b*T_ + qrow + mi*16 + l16))*D_ + h*64;
        #pragma unroll
        for (int ks=0;ks<2;++ks){
            float4 a0 = *(const float4*)(qp + ks*32 + quad*8);
            float4 a1 = *(const float4*)(qp + ks*32 + quad*8 + 4);
            S8 hh, ll;
            split2(a0.x, hh.s[0], ll.s[0]); split2(a0.y, hh.s[1], ll.s[1]);
            split2(a0.z, hh.s[2], ll.s[2]); split2(a0.w, hh.s[3], ll.s[3]);
            split2(a1.x, hh.s[4], ll.s[4]); split2(a1.y, hh.s[5], ll.s[5]);
            split2(a1.z, hh.s[6], ll.s[6]); split2(a1.w, hh.s[7], ll.s[7]);
            qh_[mi][ks] = hh.v; ql_[mi][ks] = ll.v;
        }
    }
    f32x4 o[2][4];
    #pragma unroll
    for (int mi=0;mi<2;++mi)
        #pragma unroll
        for (int i=0;i<4;++i) o[mi][i] = (f32x4){0.f,0.f,0.f,0.f};
    float m_i[2][4], l_i[2][4];
    #pragma unroll
    for (int mi=0;mi<2;++mi)
        #pragma unroll
        for (int r=0;r<4;++r){ m_i[mi][r] = -INFINITY; l_i[mi][r] = 0.f; }

    u16* Pmh = Ph + w*1024;
    u16* Pml = Pl + w*1024;

    const int kvT = 2*qi + 2;
    for (int kvt=0; kvt<kvT; ++kvt){
        __syncthreads();                     // prev-iter readers done
        #pragma unroll
        for (int i=0;i<2;++i){               // stage K/V: 512 chunks each, 2/thread
            const int ci = t + 256*i;
            const int row = ci>>3, c = ci&7;
            const int lo = swz(row, c*8);
            const size_t gk = ((size_t)(b*T_ + kvt*64 + row))*D_ + h*64 + c*8;
            *(uint4*)(Ksh + lo) = *(const uint4*)(kh + gk);
            *(uint4*)(Ksl + lo) = *(const uint4*)(kl + gk);
            const size_t gv = ((size_t)(bh*64 + row))*T_ + kvt*64 + c*8;
            *(uint4*)(Vsh + lo) = *(const uint4*)(vth + gv);
            *(uint4*)(Vsl + lo) = *(const uint4*)(vtl + gv);
        }
        __syncthreads();

        // S = Q K^T for both M-tiles
        float s[2][4][4];
        #pragma unroll
        for (int mi=0;mi<2;++mi){
            #pragma unroll
            for (int ni=0;ni<4;++ni){
                f32x4 sa = (f32x4){0.f,0.f,0.f,0.f};
                const int row = ni*16 + l16;
                #pragma unroll
                for (int ks=0;ks<2;++ks){
                    const int co = swz(row, ks*32 + quad*8);
                    short8 k8h = *(const short8*)(Ksh + co);
                    short8 k8l = *(const short8*)(Ksl + co);
                    sa = __builtin_amdgcn_mfma_f32_16x16x32_bf16(qh_[mi][ks], k8h, sa, 0,0,0);
                    sa = __builtin_amdgcn_mfma_f32_16x16x32_bf16(qh_[mi][ks], k8l, sa, 0,0,0);
                    sa = __builtin_amdgcn_mfma_f32_16x16x32_bf16(ql_[mi][ks], k8h, sa, 0,0,0);
                }
                #pragma unroll
                for (int r=0;r<4;++r) s[mi][ni][r] = sa[r]*0.125f;
            }
        }
        // causal mask iff tile max col can exceed wave min row; exact per-element
        if (kvt*64 + 63 > qrow){
            #pragma unroll
            for (int mi=0;mi<2;++mi)
                #pragma unroll
                for (int ni=0;ni<4;++ni){
                    const int colabs = kvt*64 + ni*16 + l16;
                    #pragma unroll
                    for (int r=0;r<4;++r){
                        const int rowabs = qrow + mi*16 + quad*4 + r;
                        if (colabs > rowabs) s[mi][ni][r] = -INFINITY;
                    }
                }
        }
        // online softmax per M-tile (rows live across 16 lanes of a quad)
        float alpha[2][4];
        #pragma unroll
        for (int mi=0;mi<2;++mi){
            #pragma unroll
            for (int r=0;r<4;++r){
                float rm = fmaxf(fmaxf(s[mi][0][r],s[mi][1][r]), fmaxf(s[mi][2][r],s[mi][3][r]));
                #pragma unroll
                for (int off=1; off<16; off<<=1) rm = fmaxf(rm, __shfl_xor(rm, off));
                const float mnew = fmaxf(m_i[mi][r], rm);
                alpha[mi][r] = __expf(m_i[mi][r] - mnew);
                m_i[mi][r] = mnew;
                #pragma unroll
                for (int ni=0;ni<4;++ni) s[mi][ni][r] = __expf(s[mi][ni][r] - mnew);
                float rs = s[mi][0][r]+s[mi][1][r]+s[mi][2][r]+s[mi][3][r];
                #pragma unroll
                for (int off=1; off<16; off<<=1) rs += __shfl_xor(rs, off);
                l_i[mi][r] = l_i[mi][r]*alpha[mi][r] + rs;
            }
            #pragma unroll
            for (int ni=0;ni<4;++ni)
                #pragma unroll
                for (int r=0;r<4;++r) o[mi][ni][r] *= alpha[mi][r];
        }
        // P·V, phased per M-tile through per-wave buffer (no __syncthreads):
        // same-wave LDS ops complete in order; asm pins compiler ordering.
        #pragma unroll
        for (int mi=0;mi<2;++mi){
            if (mi) __asm__ volatile("" ::: "memory");  // mi1 writes after mi0 reads
            #pragma unroll
            for (int ni=0;ni<4;++ni)
                #pragma unroll
                for (int r=0;r<4;++r){
                    u16 hh, ll; split2(s[mi][ni][r], hh, ll);
                    const int po = swz(quad*4+r, ni*16 + l16);
                    Pmh[po] = hh; Pml[po] = ll;
                }
            __asm__ volatile("s_waitcnt lgkmcnt(0)" ::: "memory");
            short8 pah[2], pal[2];
            #pragma unroll
            for (int ks=0;ks<2;++ks){
                const int po = swz(l16, ks*32 + quad*8);
                pah[ks] = *(const short8*)(Pmh + po);
                pal[ks] = *(const short8*)(Pml + po);
            }
            #pragma unroll
            for (int ni=0;ni<4;++ni){
                const int row = ni*16 + l16;
                #pragma unroll
                for (int ks=0;ks<2;++ks){
                    const int co = swz(row, ks*32 + quad*8);
                    short8 v8h = *(const short8*)(Vsh + co);
                    short8 v8l = *(const short8*)(Vsl + co);
                    o[mi][ni] = __builtin_amdgcn_mfma_f32_16x16x32_bf16(pah[ks], v8h, o[mi][ni], 0,0,0);
                    o[mi][ni] = __builtin_amdgcn_mfma_f32_16x16x32_bf16(pah[ks], v8l, o[mi][ni], 0,0,0);
                    o[mi][ni] = __builtin_amdgcn_mfma_f32_16x16x32_bf16(pal[ks], v8h, o[mi][ni], 0,0,0);
                }
            }
        }
    }
    const size_t ob = (size_t)(b*T_ + qrow);
    #pragma unroll
    for (int mi=0;mi<2;++mi)
        #pragma unroll
        for (int ni=0;ni<4;++ni){
            const int col = h*64 + ni*16 + l16;
            #pragma unroll
            for (int r=0;r<4;++r)
                att[(ob + mi*16 + quad*4 + r)*D_ + col] = o[mi][ni][r] / l_i[mi][r];
        }
}

// ---- round-3 proven f32-in GEMM (A f32, Bt f32 [N,K], bias) for out-proj ----
__global__ __launch_bounds__(256) void gemm_bt(const float* __restrict__ A,
                                               const float* __restrict__ Bt,
                                               float* __restrict__ C,
                                               const float* __restrict__ bias,
                                               int M, int N, int K)
{
    __shared__ u16 Ash[128*32], Asl[128*32];
    __shared__ u16 Bsh[128*32], Bsl[128*32];
    const int n0 = blockIdx.x*128, m0 = blockIdx.y*128;
    const int t = threadIdx.x;
    const int w = t>>6, lane = t&63, quad = lane>>4, l16 = lane&15;
    const int wm = (w>>1)*64, wn = (w&1)*64;
    f32x4 acc[4][4];
    #pragma unroll
    for (int i=0;i<4;++i)
        #pragma unroll
        for (int j=0;j<4;++j) acc[i][j] = (f32x4){0.f,0.f,0.f,0.f};
    const int kT = K >> 5;
    for (int kt=0; kt<kT; ++kt){
        const int k0 = kt*32;
        #pragma unroll
        for (int i=0;i<4;++i){
            int ci = t + 256*i;
            int row = ci>>3, c4 = ci&7;
            float4 av = *(const float4*)(A  + (size_t)(m0+row)*K + k0 + c4*4);
            float4 bv = *(const float4*)(Bt + (size_t)(n0+row)*K + k0 + c4*4);
            U4 ah, al, bh, bl;
            split2(av.x, ah.s[0], al.s[0]); split2(av.y, ah.s[1], al.s[1]);
            split2(av.z, ah.s[2], al.s[2]); split2(av.w, ah.s[3], al.s[3]);
            split2(bv.x, bh.s[0], bl.s[0]); split2(bv.y, bh.s[1], bl.s[1]);
            split2(bv.z, bh.s[2], bl.s[2]); split2(bv.w, bh.s[3], bl.s[3]);
            *(uint2*)(Ash + row*32 + c4*4) = ah.v;
            *(uint2*)(Asl + row*32 + c4*4) = al.v;
            *(uint2*)(Bsh + row*32 + c4*4) = bh.v;
            *(uint2*)(Bsl + row*32 + c4*4) = bl.v;
        }
        __syncthreads();
        short8 afh[4], afl[4], bfh[4], bfl[4];
        #pragma unroll
        for (int mi=0;mi<4;++mi){
            afh[mi] = *(const short8*)(Ash + (wm+mi*16+l16)*32 + quad*8);
            afl[mi] = *(const short8*)(Asl + (wm+mi*16+l16)*32 + quad*8);
        }
        #pragma unroll
        for (int ni=0;ni<4;++ni){
            bfh[ni] = *(const short8*)(Bsh + (wn+ni*16+l16)*32 + quad*8);
            bfl[ni] = *(const short8*)(Bsl + (wn+ni*16+l16)*32 + quad*8);
        }
        #pragma unroll
        for (int mi=0;mi<4;++mi)
            #pragma unroll
            for (int ni=0;ni<4;++ni){
                acc[mi][ni] = __builtin_amdgcn_mfma_f32_16x16x32_bf16(afh[mi], bfh[ni], acc[mi][ni], 0,0,0);
                acc[mi][ni] = __builtin_amdgcn_mfma_f32_16x16x32_bf16(afh[mi], bfl[ni], acc[mi][ni], 0,0,0);
                acc[mi][ni] = __builtin_amdgcn_mfma_f32_16x16x32_bf16(afl[mi], bfh[ni], acc[mi][ni], 0,0,0);
            }
        __syncthreads();
    }
    #pragma unroll
    for (int ni=0;ni<4;++ni){
        const int col = n0 + wn + ni*16 + l16;
        const float bv = bias ? bias[col] : 0.f;
        #pragma unroll
        for (int mi=0;mi<4;++mi){
            const int row = m0 + wm + mi*16 + quad*4;
            #pragma unroll
            for (int r=0;r<4;++r)
                C[(size_t)(row+r)*N + col] = acc[mi][ni][r] + bv;
        }
    }
}

extern "C" void kernel_launch(void* const* d_in, const int* in_sizes, int n_in,
                              void* d_out, int out_size, void* d_ws, size_t ws_size,
                              hipStream_t stream)
{
    const float* x  = (const float*)d_in[0];
    const float* Wq = (const float*)d_in[1];
    const float* Wk = (const float*)d_in[2];
    const float* Wv = (const float*)d_in[3];
    const float* Wp = (const float*)d_in[4];
    const float* bp = (const float*)d_in[5];
    float* out = (float*)d_out;

    // workspace layout (134.2 MB total, proven footprint)
    float* q   = (float*)d_ws;                 // [BT][1024] f32
    u16*  kh   = (u16*)(q + (size_t)BT*D_);    // [BT][1024] u16
    u16*  kl   = kh + (size_t)BT*D_;
    u16*  vth  = kl + (size_t)BT*D_;           // [64bh][64e][2048t] u16
    u16*  vtl  = vth + (size_t)BT*D_;
    float* att = (float*)(vtl + (size_t)BT*D_);// [BT][1024] f32
    // Wt (split) aliases the att region: dead before attn writes att
    u16*  Wth  = (u16*)att;                    // [3072][1024] u16 (6.3 MB)
    u16*  Wtl  = Wth + (size_t)3072*D_;

    pack_w  <<<dim3(16,16,3), 256, 0, stream>>>(Wq, Wk, Wv, Wth, Wtl);
    gemm_qkv<<<dim3(24, BT/128), 256, 0, stream>>>(x, Wth, Wtl, q, kh, kl, vth, vtl);
    attn    <<<dim3(T_/128, B_*H_), 256, 0, stream>>>(q, kh, kl, vth, vtl, att);
    gemm_bt <<<dim3(8, BT/128), 256, 0, stream>>>(att, Wp, out, bp, BT, D_, D_);
}

// Round 7
// 673.068 us; speedup vs baseline: 1.4252x; 1.4252x over previous
//
#include <hip/hip_runtime.h>
#include <hip/hip_bf16.h>

typedef unsigned short u16;
typedef unsigned int u32;
typedef __attribute__((ext_vector_type(8))) short short8;
typedef __attribute__((ext_vector_type(4))) float f32x4;

#define B_ 4
#define T_ 2048
#define D_ 1024
#define H_ 16
#define HS_ 64
#define BT (B_*T_)

__device__ __forceinline__ float bf2f(u16 b){ union{u32 u; float f;} v; v.u=((u32)b)<<16; return v.f; }
__device__ __forceinline__ u16 f2bf(float f){
    __hip_bfloat16 h = __float2bfloat16(f);
    union{__hip_bfloat16 h; u16 u;} v; v.h = h; return v.u;
}
// split f32 into hi/lo bf16: x ~= hi + lo
__device__ __forceinline__ void split2(float x, u16& h, u16& l){
    u16 hb = f2bf(x);
    float fh = bf2f(hb);
    h = hb; l = f2bf(x - fh);
}
union U4 { u16 s[4]; uint2 v; };
union S8 { u16 s[8]; short8 v; };

// async global->LDS, 16B per lane; LDS dest wave-linear (base + lane*16)
#define GLD16(g,l) __builtin_amdgcn_global_load_lds( \
    (__attribute__((address_space(1))) void*)(u16*)(g), \
    (__attribute__((address_space(3))) void*)(l), 16, 0, 0)

// XOR-swizzled offset into a row-major [R][64]-u16 LDS tile, 16B-chunk granularity.
// Verified conflict-free in round 5 (SQ_LDS_BANK_CONFLICT == 0).
__device__ __forceinline__ int swz(int row, int col){
    return row*64 + (((col>>3) ^ (row&7))<<3) + (col&7);
}

// ---- pack: Wt[n][d] (split hi/lo) = W_z[h][d][e], n = z*1024 + h*64 + e ----
__global__ __launch_bounds__(256) void pack_w(const float* __restrict__ Wq,
                                              const float* __restrict__ Wk,
                                              const float* __restrict__ Wv,
                                              u16* __restrict__ Wth,
                                              u16* __restrict__ Wtl)
{
    __shared__ float Tl[64*68];
    const int h = blockIdx.x, dt = blockIdx.y, z = blockIdx.z;
    const float* src = (z==0) ? Wq : ((z==1) ? Wk : Wv);
    const int t = threadIdx.x;
    const int d0 = dt*64;
    #pragma unroll
    for (int i=0;i<4;++i){
        int ci = t + 256*i;
        int dr = ci>>4, ec = ci&15;
        float4 v = *(const float4*)(src + ((size_t)h*D_ + d0+dr)*HS_ + ec*4);
        *(float4*)(Tl + dr*68 + ec*4) = v;
    }
    __syncthreads();
    #pragma unroll
    for (int i=0;i<4;++i){
        int ci = t + 256*i;
        int e = ci>>4, dc = ci&15;
        U4 hh, ll;
        #pragma unroll
        for (int j=0;j<4;++j){
            float f = Tl[(dc*4+j)*68 + e];
            split2(f, hh.s[j], ll.s[j]);
        }
        int n = z*D_ + h*HS_ + e;
        *(uint2*)(Wth + (size_t)n*D_ + d0 + dc*4) = hh.v;
        *(uint2*)(Wtl + (size_t)n*D_ + d0 + dc*4) = ll.v;
    }
}

// ---- QKV GEMM: qkv[t][col] = x[t][:]·Wt[col][:], col in [0,3072) ----
__global__ __launch_bounds__(256) void gemm_qkv(const float* __restrict__ x,
                                                const u16* __restrict__ Wth,
                                                const u16* __restrict__ Wtl,
                                                float* __restrict__ qo,
                                                u16* __restrict__ kho, u16* __restrict__ klo,
                                                u16* __restrict__ vth, u16* __restrict__ vtl)
{
    __shared__ u16 Ash[128*32], Asl[128*32];
    __shared__ u16 Bsh[128*32], Bsl[128*32];
    const int n0 = blockIdx.x*128, m0 = blockIdx.y*128;
    const int t = threadIdx.x;
    const int w = t>>6, lane = t&63, quad = lane>>4, l16 = lane&15;
    const int wm = (w>>1)*64, wn = (w&1)*64;
    f32x4 acc[4][4];
    #pragma unroll
    for (int i=0;i<4;++i)
        #pragma unroll
        for (int j=0;j<4;++j) acc[i][j] = (f32x4){0.f,0.f,0.f,0.f};
    for (int kt=0; kt<32; ++kt){
        const int k0 = kt*32;
        #pragma unroll
        for (int i=0;i<2;++i){           // B: async 16B chunks, wave-linear LDS dest
            int ci = t + 256*i;
            int row = ci>>2, c = ci&3;
            GLD16(Wth + (size_t)(n0+row)*D_ + k0 + c*8, Bsh + ci*8);
            GLD16(Wtl + (size_t)(n0+row)*D_ + k0 + c*8, Bsl + ci*8);
        }
        #pragma unroll
        for (int i=0;i<4;++i){           // A: f32 load + split
            int ci = t + 256*i;
            int row = ci>>3, c4 = ci&7;
            float4 av = *(const float4*)(x + (size_t)(m0+row)*D_ + k0 + c4*4);
            U4 hh, ll;
            split2(av.x, hh.s[0], ll.s[0]); split2(av.y, hh.s[1], ll.s[1]);
            split2(av.z, hh.s[2], ll.s[2]); split2(av.w, hh.s[3], ll.s[3]);
            *(uint2*)(Ash + row*32 + c4*4) = hh.v;
            *(uint2*)(Asl + row*32 + c4*4) = ll.v;
        }
        __syncthreads();
        short8 afh[4], afl[4], bfh[4], bfl[4];
        #pragma unroll
        for (int mi=0;mi<4;++mi){
            afh[mi] = *(const short8*)(Ash + (wm+mi*16+l16)*32 + quad*8);
            afl[mi] = *(const short8*)(Asl + (wm+mi*16+l16)*32 + quad*8);
        }
        #pragma unroll
        for (int ni=0;ni<4;++ni){
            bfh[ni] = *(const short8*)(Bsh + (wn+ni*16+l16)*32 + quad*8);
            bfl[ni] = *(const short8*)(Bsl + (wn+ni*16+l16)*32 + quad*8);
        }
        #pragma unroll
        for (int mi=0;mi<4;++mi)
            #pragma unroll
            for (int ni=0;ni<4;++ni){
                acc[mi][ni] = __builtin_amdgcn_mfma_f32_16x16x32_bf16(afh[mi], bfh[ni], acc[mi][ni], 0,0,0);
                acc[mi][ni] = __builtin_amdgcn_mfma_f32_16x16x32_bf16(afh[mi], bfl[ni], acc[mi][ni], 0,0,0);
                acc[mi][ni] = __builtin_amdgcn_mfma_f32_16x16x32_bf16(afl[mi], bfh[ni], acc[mi][ni], 0,0,0);
            }
        __syncthreads();
    }
    const int z = n0 >> 10;              // block-uniform (128 | 1024)
    if (z == 0){
        #pragma unroll
        for (int ni=0;ni<4;++ni){
            const int nloc = (n0 & 1023) + wn + ni*16 + l16;
            #pragma unroll
            for (int mi=0;mi<4;++mi){
                const int row = m0 + wm + mi*16 + quad*4;
                #pragma unroll
                for (int r=0;r<4;++r)
                    qo[(size_t)(row+r)*D_ + nloc] = acc[mi][ni][r];
            }
        }
    } else if (z == 1){
        #pragma unroll
        for (int ni=0;ni<4;++ni){
            const int nloc = (n0 & 1023) + wn + ni*16 + l16;
            #pragma unroll
            for (int mi=0;mi<4;++mi){
                const int row = m0 + wm + mi*16 + quad*4;
                #pragma unroll
                for (int r=0;r<4;++r){
                    u16 hh, ll; split2(acc[mi][ni][r], hh, ll);
                    kho[(size_t)(row+r)*D_ + nloc] = hh;
                    klo[(size_t)(row+r)*D_ + nloc] = ll;
                }
            }
        }
    } else {
        #pragma unroll
        for (int ni=0;ni<4;++ni){
            const int nloc = (n0 & 1023) + wn + ni*16 + l16;
            const int hloc = nloc>>6, e = nloc&63;
            #pragma unroll
            for (int mi=0;mi<4;++mi){
                const int rowb = m0 + wm + mi*16 + quad*4;   // multiple of 4
                const int bidx = rowb >> 11, tloc = rowb & 2047;
                U4 hh, ll;
                #pragma unroll
                for (int r=0;r<4;++r) split2(acc[mi][ni][r], hh.s[r], ll.s[r]);
                const size_t adr = ((size_t)((bidx*16 + hloc)*64 + e))*T_ + tloc;
                *(uint2*)(vth + adr) = hh.v;
                *(uint2*)(vtl + adr) = ll.v;
            }
        }
    }
}

// ---- causal flash attention; q-tile 128, 8 waves x 16 q-rows (round-5 proven),
// + register prefetch of next K/V tile to hide global latency behind compute ----
__global__ __launch_bounds__(512) void attn(const float* __restrict__ q,
                                            const u16* __restrict__ kh, const u16* __restrict__ kl,
                                            const u16* __restrict__ vth, const u16* __restrict__ vtl,
                                            float* __restrict__ att)
{
    __shared__ u16 Ksh[64*64], Ksl[64*64];   // [kv][e], swizzled
    __shared__ u16 Vsh[64*64], Vsl[64*64];   // [e][kv], swizzled
    __shared__ u16 Ph[8*16*64], Pl[8*16*64]; // per-wave [16][64], swizzled
    const int qi = blockIdx.x;               // q-tile of 128
    const int bh = blockIdx.y;
    const int b = bh >> 4, h = bh & 15;
    const int t = threadIdx.x;
    const int w = t>>6, lane = t&63, quad = lane>>4, l16 = lane&15;
    const int qrow = qi*128 + w*16;          // wave's absolute q base

    short8 qh_[2], ql_[2];
    {
        const float* qp = q + ((size_t)(b*T_ + qrow + l16))*D_ + h*64;
        #pragma unroll
        for (int ks=0;ks<2;++ks){
            float4 a0 = *(const float4*)(qp + ks*32 + quad*8);
            float4 a1 = *(const float4*)(qp + ks*32 + quad*8 + 4);
            S8 hh, ll;
            split2(a0.x, hh.s[0], ll.s[0]); split2(a0.y, hh.s[1], ll.s[1]);
            split2(a0.z, hh.s[2], ll.s[2]); split2(a0.w, hh.s[3], ll.s[3]);
            split2(a1.x, hh.s[4], ll.s[4]); split2(a1.y, hh.s[5], ll.s[5]);
            split2(a1.z, hh.s[6], ll.s[6]); split2(a1.w, hh.s[7], ll.s[7]);
            qh_[ks] = hh.v; ql_[ks] = ll.v;
        }
    }
    f32x4 o[4];
    #pragma unroll
    for (int i=0;i<4;++i) o[i] = (f32x4){0.f,0.f,0.f,0.f};
    float m_i[4], l_i[4];
    #pragma unroll
    for (int r=0;r<4;++r){ m_i[r] = -INFINITY; l_i[r] = 0.f; }

    u16* Pmh = Ph + w*1024;
    u16* Pml = Pl + w*1024;

    // staging geometry: 512 threads = 64 rows x 8 chunks, 1 uint4/thread/array
    const int srow = t>>3, sc = t&7;
    const int slo = swz(srow, sc*8);
    // register prefetch buffers (+16 VGPR)
    uint4 pkh, pkl, pvh, pvl;
    {   // tile 0
        const size_t gk = ((size_t)(b*T_ + srow))*D_ + h*64 + sc*8;
        pkh = *(const uint4*)(kh + gk);
        pkl = *(const uint4*)(kl + gk);
        const size_t gv = ((size_t)(bh*64 + srow))*T_ + sc*8;
        pvh = *(const uint4*)(vth + gv);
        pvl = *(const uint4*)(vtl + gv);
    }

    const int kvT = 2*qi + 2;
    for (int kvt=0; kvt<kvT; ++kvt){
        __syncthreads();                     // prev-iter readers done
        *(uint4*)(Ksh + slo) = pkh;
        *(uint4*)(Ksl + slo) = pkl;
        *(uint4*)(Vsh + slo) = pvh;
        *(uint4*)(Vsl + slo) = pvl;
        if (kvt+1 < kvT){                    // prefetch next tile (block-uniform)
            const size_t gk = ((size_t)(b*T_ + (kvt+1)*64 + srow))*D_ + h*64 + sc*8;
            pkh = *(const uint4*)(kh + gk);
            pkl = *(const uint4*)(kl + gk);
            const size_t gv = ((size_t)(bh*64 + srow))*T_ + (kvt+1)*64 + sc*8;
            pvh = *(const uint4*)(vth + gv);
            pvl = *(const uint4*)(vtl + gv);
        }
        __syncthreads();

        float s[4][4];
        #pragma unroll
        for (int ni=0;ni<4;++ni){
            f32x4 sa = (f32x4){0.f,0.f,0.f,0.f};
            const int row = ni*16 + l16;
            #pragma unroll
            for (int ks=0;ks<2;++ks){
                const int co = swz(row, ks*32 + quad*8);
                short8 k8h = *(const short8*)(Ksh + co);
                short8 k8l = *(const short8*)(Ksl + co);
                sa = __builtin_amdgcn_mfma_f32_16x16x32_bf16(qh_[ks], k8h, sa, 0,0,0);
                sa = __builtin_amdgcn_mfma_f32_16x16x32_bf16(qh_[ks], k8l, sa, 0,0,0);
                sa = __builtin_amdgcn_mfma_f32_16x16x32_bf16(ql_[ks], k8h, sa, 0,0,0);
            }
            #pragma unroll
            for (int r=0;r<4;++r) s[ni][r] = sa[r]*0.125f;
        }
        // causal mask iff tile max col can exceed wave MIN row (round-5 proven)
        if (kvt*64 + 63 > qrow){
            #pragma unroll
            for (int ni=0;ni<4;++ni){
                const int colabs = kvt*64 + ni*16 + l16;
                #pragma unroll
                for (int r=0;r<4;++r){
                    const int rowabs = qrow + quad*4 + r;
                    if (colabs > rowabs) s[ni][r] = -INFINITY;
                }
            }
        }
        float mnew[4], alpha[4];
        #pragma unroll
        for (int r=0;r<4;++r){
            float rm = fmaxf(fmaxf(s[0][r],s[1][r]), fmaxf(s[2][r],s[3][r]));
            #pragma unroll
            for (int off=1; off<16; off<<=1) rm = fmaxf(rm, __shfl_xor(rm, off));
            mnew[r] = fmaxf(m_i[r], rm);
            alpha[r] = __expf(m_i[r] - mnew[r]);
        }
        float p[4][4];
        #pragma unroll
        for (int ni=0;ni<4;++ni)
            #pragma unroll
            for (int r=0;r<4;++r) p[ni][r] = __expf(s[ni][r] - mnew[r]);
        #pragma unroll
        for (int r=0;r<4;++r){
            float rs = p[0][r]+p[1][r]+p[2][r]+p[3][r];
            #pragma unroll
            for (int off=1; off<16; off<<=1) rs += __shfl_xor(rs, off);
            l_i[r] = l_i[r]*alpha[r] + rs;
            m_i[r] = mnew[r];
        }
        #pragma unroll
        for (int ni=0;ni<4;++ni)
            #pragma unroll
            for (int r=0;r<4;++r) o[ni][r] *= alpha[r];
        // P: C-layout -> swizzled LDS -> A-layout
        #pragma unroll
        for (int ni=0;ni<4;++ni)
            #pragma unroll
            for (int r=0;r<4;++r){
                u16 hh, ll; split2(p[ni][r], hh, ll);
                const int po = swz(quad*4+r, ni*16 + l16);
                Pmh[po] = hh; Pml[po] = ll;
            }
        __syncthreads();                     // fence scalar writes vs vector reads
        short8 pah[2], pal[2];
        #pragma unroll
        for (int ks=0;ks<2;++ks){
            const int po = swz(l16, ks*32 + quad*8);
            pah[ks] = *(const short8*)(Pmh + po);
            pal[ks] = *(const short8*)(Pml + po);
        }
        #pragma unroll
        for (int ni=0;ni<4;++ni){
            const int row = ni*16 + l16;
            #pragma unroll
            for (int ks=0;ks<2;++ks){
                const int co = swz(row, ks*32 + quad*8);
                short8 v8h = *(const short8*)(Vsh + co);
                short8 v8l = *(const short8*)(Vsl + co);
                o[ni] = __builtin_amdgcn_mfma_f32_16x16x32_bf16(pah[ks], v8h, o[ni], 0,0,0);
                o[ni] = __builtin_amdgcn_mfma_f32_16x16x32_bf16(pah[ks], v8l, o[ni], 0,0,0);
                o[ni] = __builtin_amdgcn_mfma_f32_16x16x32_bf16(pal[ks], v8h, o[ni], 0,0,0);
            }
        }
    }
    const size_t ob = (size_t)(b*T_ + qrow);
    #pragma unroll
    for (int ni=0;ni<4;++ni){
        const int col = h*64 + ni*16 + l16;
        #pragma unroll
        for (int r=0;r<4;++r)
            att[(ob + quad*4 + r)*D_ + col] = o[ni][r] / l_i[r];
    }
}

// ---- round-3 proven f32-in GEMM (A f32, Bt f32 [N,K], bias) for out-proj ----
__global__ __launch_bounds__(256) void gemm_bt(const float* __restrict__ A,
                                               const float* __restrict__ Bt,
                                               float* __restrict__ C,
                                               const float* __restrict__ bias,
                                               int M, int N, int K)
{
    __shared__ u16 Ash[128*32], Asl[128*32];
    __shared__ u16 Bsh[128*32], Bsl[128*32];
    const int n0 = blockIdx.x*128, m0 = blockIdx.y*128;
    const int t = threadIdx.x;
    const int w = t>>6, lane = t&63, quad = lane>>4, l16 = lane&15;
    const int wm = (w>>1)*64, wn = (w&1)*64;
    f32x4 acc[4][4];
    #pragma unroll
    for (int i=0;i<4;++i)
        #pragma unroll
        for (int j=0;j<4;++j) acc[i][j] = (f32x4){0.f,0.f,0.f,0.f};
    const int kT = K >> 5;
    for (int kt=0; kt<kT; ++kt){
        const int k0 = kt*32;
        #pragma unroll
        for (int i=0;i<4;++i){
            int ci = t + 256*i;
            int row = ci>>3, c4 = ci&7;
            float4 av = *(const float4*)(A  + (size_t)(m0+row)*K + k0 + c4*4);
            float4 bv = *(const float4*)(Bt + (size_t)(n0+row)*K + k0 + c4*4);
            U4 ah, al, bh, bl;
            split2(av.x, ah.s[0], al.s[0]); split2(av.y, ah.s[1], al.s[1]);
            split2(av.z, ah.s[2], al.s[2]); split2(av.w, ah.s[3], al.s[3]);
            split2(bv.x, bh.s[0], bl.s[0]); split2(bv.y, bh.s[1], bl.s[1]);
            split2(bv.z, bh.s[2], bl.s[2]); split2(bv.w, bh.s[3], bl.s[3]);
            *(uint2*)(Ash + row*32 + c4*4) = ah.v;
            *(uint2*)(Asl + row*32 + c4*4) = al.v;
            *(uint2*)(Bsh + row*32 + c4*4) = bh.v;
            *(uint2*)(Bsl + row*32 + c4*4) = bl.v;
        }
        __syncthreads();
        short8 afh[4], afl[4], bfh[4], bfl[4];
        #pragma unroll
        for (int mi=0;mi<4;++mi){
            afh[mi] = *(const short8*)(Ash + (wm+mi*16+l16)*32 + quad*8);
            afl[mi] = *(const short8*)(Asl + (wm+mi*16+l16)*32 + quad*8);
        }
        #pragma unroll
        for (int ni=0;ni<4;++ni){
            bfh[ni] = *(const short8*)(Bsh + (wn+ni*16+l16)*32 + quad*8);
            bfl[ni] = *(const short8*)(Bsl + (wn+ni*16+l16)*32 + quad*8);
        }
        #pragma unroll
        for (int mi=0;mi<4;++mi)
            #pragma unroll
            for (int ni=0;ni<4;++ni){
                acc[mi][ni] = __builtin_amdgcn_mfma_f32_16x16x32_bf16(afh[mi], bfh[ni], acc[mi][ni], 0,0,0);
                acc[mi][ni] = __builtin_amdgcn_mfma_f32_16x16x32_bf16(afh[mi], bfl[ni], acc[mi][ni], 0,0,0);
                acc[mi][ni] = __builtin_amdgcn_mfma_f32_16x16x32_bf16(afl[mi], bfh[ni], acc[mi][ni], 0,0,0);
            }
        __syncthreads();
    }
    #pragma unroll
    for (int ni=0;ni<4;++ni){
        const int col = n0 + wn + ni*16 + l16;
        const float bv = bias ? bias[col] : 0.f;
        #pragma unroll
        for (int mi=0;mi<4;++mi){
            const int row = m0 + wm + mi*16 + quad*4;
            #pragma unroll
            for (int r=0;r<4;++r)
                C[(size_t)(row+r)*N + col] = acc[mi][ni][r] + bv;
        }
    }
}

extern "C" void kernel_launch(void* const* d_in, const int* in_sizes, int n_in,
                              void* d_out, int out_size, void* d_ws, size_t ws_size,
                              hipStream_t stream)
{
    const float* x  = (const float*)d_in[0];
    const float* Wq = (const float*)d_in[1];
    const float* Wk = (const float*)d_in[2];
    const float* Wv = (const float*)d_in[3];
    const float* Wp = (const float*)d_in[4];
    const float* bp = (const float*)d_in[5];
    float* out = (float*)d_out;

    // workspace layout (134.2 MB total, proven footprint)
    float* q   = (float*)d_ws;                 // [BT][1024] f32
    u16*  kh   = (u16*)(q + (size_t)BT*D_);    // [BT][1024] u16
    u16*  kl   = kh + (size_t)BT*D_;
    u16*  vth  = kl + (size_t)BT*D_;           // [64bh][64e][2048t] u16
    u16*  vtl  = vth + (size_t)BT*D_;
    float* att = (float*)(vtl + (size_t)BT*D_);// [BT][1024] f32
    // Wt (split) aliases the att region: dead before attn writes att
    u16*  Wth  = (u16*)att;                    // [3072][1024] u16 (6.3 MB)
    u16*  Wtl  = Wth + (size_t)3072*D_;

    pack_w  <<<dim3(16,16,3), 256, 0, stream>>>(Wq, Wk, Wv, Wth, Wtl);
    gemm_qkv<<<dim3(24, BT/128), 256, 0, stream>>>(x, Wth, Wtl, q, kh, kl, vth, vtl);
    attn    <<<dim3(T_/128, B_*H_), 512, 0, stream>>>(q, kh, kl, vth, vtl, att);
    gemm_bt <<<dim3(8, BT/128), 256, 0, stream>>>(att, Wp, out, bp, BT, D_, D_);
}

// Round 8
// 672.762 us; speedup vs baseline: 1.4258x; 1.0005x over previous
//
#include <hip/hip_runtime.h>
#include <hip/hip_bf16.h>

typedef unsigned short u16;
typedef unsigned int u32;
typedef __attribute__((ext_vector_type(8))) short short8;
typedef __attribute__((ext_vector_type(4))) float f32x4;

#define B_ 4
#define T_ 2048
#define D_ 1024
#define H_ 16
#define HS_ 64
#define BT (B_*T_)

__device__ __forceinline__ float bf2f(u16 b){ union{u32 u; float f;} v; v.u=((u32)b)<<16; return v.f; }
__device__ __forceinline__ u16 f2bf(float f){
    __hip_bfloat16 h = __float2bfloat16(f);
    union{__hip_bfloat16 h; u16 u;} v; v.h = h; return v.u;
}
// split f32 into hi/lo bf16: x ~= hi + lo
__device__ __forceinline__ void split2(float x, u16& h, u16& l){
    u16 hb = f2bf(x);
    float fh = bf2f(hb);
    h = hb; l = f2bf(x - fh);
}
union U4 { u16 s[4]; uint2 v; };
union S8 { u16 s[8]; short8 v; };

// async global->LDS, 16B per lane; LDS dest wave-linear (base + lane*16)
#define GLD16(g,l) __builtin_amdgcn_global_load_lds( \
    (__attribute__((address_space(1))) void*)(u16*)(g), \
    (__attribute__((address_space(3))) void*)(l), 16, 0, 0)

// XOR-swizzled offset into a row-major [R][64]-u16 LDS tile, 16B-chunk granularity.
// Verified conflict-free in round 5 (SQ_LDS_BANK_CONFLICT == 0).
__device__ __forceinline__ int swz(int row, int col){
    return row*64 + (((col>>3) ^ (row&7))<<3) + (col&7);
}

// ---- pack: Wt[n][d] (split hi/lo) = W_z[h][d][e], n = z*1024 + h*64 + e ----
__global__ __launch_bounds__(256) void pack_w(const float* __restrict__ Wq,
                                              const float* __restrict__ Wk,
                                              const float* __restrict__ Wv,
                                              u16* __restrict__ Wth,
                                              u16* __restrict__ Wtl)
{
    __shared__ float Tl[64*68];
    const int h = blockIdx.x, dt = blockIdx.y, z = blockIdx.z;
    const float* src = (z==0) ? Wq : ((z==1) ? Wk : Wv);
    const int t = threadIdx.x;
    const int d0 = dt*64;
    #pragma unroll
    for (int i=0;i<4;++i){
        int ci = t + 256*i;
        int dr = ci>>4, ec = ci&15;
        float4 v = *(const float4*)(src + ((size_t)h*D_ + d0+dr)*HS_ + ec*4);
        *(float4*)(Tl + dr*68 + ec*4) = v;
    }
    __syncthreads();
    #pragma unroll
    for (int i=0;i<4;++i){
        int ci = t + 256*i;
        int e = ci>>4, dc = ci&15;
        U4 hh, ll;
        #pragma unroll
        for (int j=0;j<4;++j){
            float f = Tl[(dc*4+j)*68 + e];
            split2(f, hh.s[j], ll.s[j]);
        }
        int n = z*D_ + h*HS_ + e;
        *(uint2*)(Wth + (size_t)n*D_ + d0 + dc*4) = hh.v;
        *(uint2*)(Wtl + (size_t)n*D_ + d0 + dc*4) = ll.v;
    }
}

// ---- QKV GEMM: qkv[t][col] = x[t][:]·Wt[col][:], col in [0,3072) ----
__global__ __launch_bounds__(256) void gemm_qkv(const float* __restrict__ x,
                                                const u16* __restrict__ Wth,
                                                const u16* __restrict__ Wtl,
                                                float* __restrict__ qo,
                                                u16* __restrict__ kho, u16* __restrict__ klo,
                                                u16* __restrict__ vth, u16* __restrict__ vtl)
{
    __shared__ u16 Ash[128*32], Asl[128*32];
    __shared__ u16 Bsh[128*32], Bsl[128*32];
    const int n0 = blockIdx.x*128, m0 = blockIdx.y*128;
    const int t = threadIdx.x;
    const int w = t>>6, lane = t&63, quad = lane>>4, l16 = lane&15;
    const int wm = (w>>1)*64, wn = (w&1)*64;
    f32x4 acc[4][4];
    #pragma unroll
    for (int i=0;i<4;++i)
        #pragma unroll
        for (int j=0;j<4;++j) acc[i][j] = (f32x4){0.f,0.f,0.f,0.f};
    for (int kt=0; kt<32; ++kt){
        const int k0 = kt*32;
        #pragma unroll
        for (int i=0;i<2;++i){           // B: async 16B chunks, wave-linear LDS dest
            int ci = t + 256*i;
            int row = ci>>2, c = ci&3;
            GLD16(Wth + (size_t)(n0+row)*D_ + k0 + c*8, Bsh + ci*8);
            GLD16(Wtl + (size_t)(n0+row)*D_ + k0 + c*8, Bsl + ci*8);
        }
        #pragma unroll
        for (int i=0;i<4;++i){           // A: f32 load + split
            int ci = t + 256*i;
            int row = ci>>3, c4 = ci&7;
            float4 av = *(const float4*)(x + (size_t)(m0+row)*D_ + k0 + c4*4);
            U4 hh, ll;
            split2(av.x, hh.s[0], ll.s[0]); split2(av.y, hh.s[1], ll.s[1]);
            split2(av.z, hh.s[2], ll.s[2]); split2(av.w, hh.s[3], ll.s[3]);
            *(uint2*)(Ash + row*32 + c4*4) = hh.v;
            *(uint2*)(Asl + row*32 + c4*4) = ll.v;
        }
        __syncthreads();
        short8 afh[4], afl[4], bfh[4], bfl[4];
        #pragma unroll
        for (int mi=0;mi<4;++mi){
            afh[mi] = *(const short8*)(Ash + (wm+mi*16+l16)*32 + quad*8);
            afl[mi] = *(const short8*)(Asl + (wm+mi*16+l16)*32 + quad*8);
        }
        #pragma unroll
        for (int ni=0;ni<4;++ni){
            bfh[ni] = *(const short8*)(Bsh + (wn+ni*16+l16)*32 + quad*8);
            bfl[ni] = *(const short8*)(Bsl + (wn+ni*16+l16)*32 + quad*8);
        }
        #pragma unroll
        for (int mi=0;mi<4;++mi)
            #pragma unroll
            for (int ni=0;ni<4;++ni){
                acc[mi][ni] = __builtin_amdgcn_mfma_f32_16x16x32_bf16(afh[mi], bfh[ni], acc[mi][ni], 0,0,0);
                acc[mi][ni] = __builtin_amdgcn_mfma_f32_16x16x32_bf16(afh[mi], bfl[ni], acc[mi][ni], 0,0,0);
                acc[mi][ni] = __builtin_amdgcn_mfma_f32_16x16x32_bf16(afl[mi], bfh[ni], acc[mi][ni], 0,0,0);
            }
        __syncthreads();
    }
    const int z = n0 >> 10;              // block-uniform (128 | 1024)
    if (z == 0){
        #pragma unroll
        for (int ni=0;ni<4;++ni){
            const int nloc = (n0 & 1023) + wn + ni*16 + l16;
            #pragma unroll
            for (int mi=0;mi<4;++mi){
                const int row = m0 + wm + mi*16 + quad*4;
                #pragma unroll
                for (int r=0;r<4;++r)
                    qo[(size_t)(row+r)*D_ + nloc] = acc[mi][ni][r];
            }
        }
    } else if (z == 1){
        #pragma unroll
        for (int ni=0;ni<4;++ni){
            const int nloc = (n0 & 1023) + wn + ni*16 + l16;
            #pragma unroll
            for (int mi=0;mi<4;++mi){
                const int row = m0 + wm + mi*16 + quad*4;
                #pragma unroll
                for (int r=0;r<4;++r){
                    u16 hh, ll; split2(acc[mi][ni][r], hh, ll);
                    kho[(size_t)(row+r)*D_ + nloc] = hh;
                    klo[(size_t)(row+r)*D_ + nloc] = ll;
                }
            }
        }
    } else {
        #pragma unroll
        for (int ni=0;ni<4;++ni){
            const int nloc = (n0 & 1023) + wn + ni*16 + l16;
            const int hloc = nloc>>6, e = nloc&63;
            #pragma unroll
            for (int mi=0;mi<4;++mi){
                const int rowb = m0 + wm + mi*16 + quad*4;   // multiple of 4
                const int bidx = rowb >> 11, tloc = rowb & 2047;
                U4 hh, ll;
                #pragma unroll
                for (int r=0;r<4;++r) split2(acc[mi][ni][r], hh.s[r], ll.s[r]);
                const size_t adr = ((size_t)((bidx*16 + hloc)*64 + e))*T_ + tloc;
                *(uint2*)(vth + adr) = hh.v;
                *(uint2*)(vtl + adr) = ll.v;
            }
        }
    }
}

// ---- causal flash attention; q-tile 128, 8 waves x 16 q-rows, prefetch regs,
// phased P (h then l) through one per-wave buffer -> 48 KB LDS, 3 blocks/CU,
// heavy-first block order ----
__global__ __launch_bounds__(512) void attn(const float* __restrict__ q,
                                            const u16* __restrict__ kh, const u16* __restrict__ kl,
                                            const u16* __restrict__ vth, const u16* __restrict__ vtl,
                                            float* __restrict__ att)
{
    __shared__ u16 Ksh[64*64], Ksl[64*64];   // [kv][e], swizzled (16 KB)
    __shared__ u16 Vsh[64*64], Vsl[64*64];   // [e][kv], swizzled (16 KB)
    __shared__ u16 Pb[8*16*64];              // per-wave [16][64], phased h/l (16 KB)
    const int qi = gridDim.x - 1 - blockIdx.x;   // heavy-first scheduling
    const int bh = blockIdx.y;
    const int b = bh >> 4, h = bh & 15;
    const int t = threadIdx.x;
    const int w = t>>6, lane = t&63, quad = lane>>4, l16 = lane&15;
    const int qrow = qi*128 + w*16;          // wave's absolute q base

    short8 qh_[2], ql_[2];
    {
        const float* qp = q + ((size_t)(b*T_ + qrow + l16))*D_ + h*64;
        #pragma unroll
        for (int ks=0;ks<2;++ks){
            float4 a0 = *(const float4*)(qp + ks*32 + quad*8);
            float4 a1 = *(const float4*)(qp + ks*32 + quad*8 + 4);
            S8 hh, ll;
            split2(a0.x, hh.s[0], ll.s[0]); split2(a0.y, hh.s[1], ll.s[1]);
            split2(a0.z, hh.s[2], ll.s[2]); split2(a0.w, hh.s[3], ll.s[3]);
            split2(a1.x, hh.s[4], ll.s[4]); split2(a1.y, hh.s[5], ll.s[5]);
            split2(a1.z, hh.s[6], ll.s[6]); split2(a1.w, hh.s[7], ll.s[7]);
            qh_[ks] = hh.v; ql_[ks] = ll.v;
        }
    }
    f32x4 o[4];
    #pragma unroll
    for (int i=0;i<4;++i) o[i] = (f32x4){0.f,0.f,0.f,0.f};
    float m_i[4], l_i[4];
    #pragma unroll
    for (int r=0;r<4;++r){ m_i[r] = -INFINITY; l_i[r] = 0.f; }

    u16* Pm = Pb + w*1024;

    // staging geometry: 512 threads = 64 rows x 8 chunks, 1 uint4/thread/array
    const int srow = t>>3, sc = t&7;
    const int slo = swz(srow, sc*8);
    uint4 pkh, pkl, pvh, pvl;                // register prefetch (round-7 proven)
    {   // tile 0
        const size_t gk = ((size_t)(b*T_ + srow))*D_ + h*64 + sc*8;
        pkh = *(const uint4*)(kh + gk);
        pkl = *(const uint4*)(kl + gk);
        const size_t gv = ((size_t)(bh*64 + srow))*T_ + sc*8;
        pvh = *(const uint4*)(vth + gv);
        pvl = *(const uint4*)(vtl + gv);
    }

    const int kvT = 2*qi + 2;
    for (int kvt=0; kvt<kvT; ++kvt){
        __syncthreads();                     // prev-iter readers done
        *(uint4*)(Ksh + slo) = pkh;
        *(uint4*)(Ksl + slo) = pkl;
        *(uint4*)(Vsh + slo) = pvh;
        *(uint4*)(Vsl + slo) = pvl;
        if (kvt+1 < kvT){                    // prefetch next tile (block-uniform)
            const size_t gk = ((size_t)(b*T_ + (kvt+1)*64 + srow))*D_ + h*64 + sc*8;
            pkh = *(const uint4*)(kh + gk);
            pkl = *(const uint4*)(kl + gk);
            const size_t gv = ((size_t)(bh*64 + srow))*T_ + (kvt+1)*64 + sc*8;
            pvh = *(const uint4*)(vth + gv);
            pvl = *(const uint4*)(vtl + gv);
        }
        __syncthreads();

        float s[4][4];
        #pragma unroll
        for (int ni=0;ni<4;++ni){
            f32x4 sa = (f32x4){0.f,0.f,0.f,0.f};
            const int row = ni*16 + l16;
            #pragma unroll
            for (int ks=0;ks<2;++ks){
                const int co = swz(row, ks*32 + quad*8);
                short8 k8h = *(const short8*)(Ksh + co);
                short8 k8l = *(const short8*)(Ksl + co);
                sa = __builtin_amdgcn_mfma_f32_16x16x32_bf16(qh_[ks], k8h, sa, 0,0,0);
                sa = __builtin_amdgcn_mfma_f32_16x16x32_bf16(qh_[ks], k8l, sa, 0,0,0);
                sa = __builtin_amdgcn_mfma_f32_16x16x32_bf16(ql_[ks], k8h, sa, 0,0,0);
            }
            #pragma unroll
            for (int r=0;r<4;++r) s[ni][r] = sa[r]*0.125f;
        }
        // causal mask iff tile max col can exceed wave MIN row (round-5 proven)
        if (kvt*64 + 63 > qrow){
            #pragma unroll
            for (int ni=0;ni<4;++ni){
                const int colabs = kvt*64 + ni*16 + l16;
                #pragma unroll
                for (int r=0;r<4;++r){
                    const int rowabs = qrow + quad*4 + r;
                    if (colabs > rowabs) s[ni][r] = -INFINITY;
                }
            }
        }
        float alpha[4];
        #pragma unroll
        for (int r=0;r<4;++r){
            float rm = fmaxf(fmaxf(s[0][r],s[1][r]), fmaxf(s[2][r],s[3][r]));
            #pragma unroll
            for (int off=1; off<16; off<<=1) rm = fmaxf(rm, __shfl_xor(rm, off));
            const float mnew = fmaxf(m_i[r], rm);
            alpha[r] = __expf(m_i[r] - mnew);
            m_i[r] = mnew;
            #pragma unroll
            for (int ni=0;ni<4;++ni) s[ni][r] = __expf(s[ni][r] - mnew);  // in place
            float rs = s[0][r]+s[1][r]+s[2][r]+s[3][r];
            #pragma unroll
            for (int off=1; off<16; off<<=1) rs += __shfl_xor(rs, off);
            l_i[r] = l_i[r]*alpha[r] + rs;
        }
        #pragma unroll
        for (int ni=0;ni<4;++ni)
            #pragma unroll
            for (int r=0;r<4;++r) o[ni][r] *= alpha[r];

        // ---- P phase h: write hi parts, read A-frag (same-wave, in-order LDS) ----
        #pragma unroll
        for (int ni=0;ni<4;++ni)
            #pragma unroll
            for (int r=0;r<4;++r){
                u16 hh, ll; split2(s[ni][r], hh, ll);
                Pm[swz(quad*4+r, ni*16 + l16)] = hh;
            }
        __asm__ volatile("s_waitcnt lgkmcnt(0)" ::: "memory");
        short8 pah[2];
        #pragma unroll
        for (int ks=0;ks<2;++ks)
            pah[ks] = *(const short8*)(Pm + swz(l16, ks*32 + quad*8));
        __asm__ volatile("" ::: "memory");   // keep reads before the l-overwrite
        // ---- P phase l: overwrite with lo parts, read ----
        #pragma unroll
        for (int ni=0;ni<4;++ni)
            #pragma unroll
            for (int r=0;r<4;++r){
                u16 hh, ll; split2(s[ni][r], hh, ll);
                Pm[swz(quad*4+r, ni*16 + l16)] = ll;
            }
        __asm__ volatile("s_waitcnt lgkmcnt(0)" ::: "memory");
        short8 pal[2];
        #pragma unroll
        for (int ks=0;ks<2;++ks)
            pal[ks] = *(const short8*)(Pm + swz(l16, ks*32 + quad*8));
        __asm__ volatile("" ::: "memory");   // keep reads before next-iter overwrite

        #pragma unroll
        for (int ni=0;ni<4;++ni){
            const int row = ni*16 + l16;
            #pragma unroll
            for (int ks=0;ks<2;++ks){
                const int co = swz(row, ks*32 + quad*8);
                short8 v8h = *(const short8*)(Vsh + co);
                short8 v8l = *(const short8*)(Vsl + co);
                o[ni] = __builtin_amdgcn_mfma_f32_16x16x32_bf16(pah[ks], v8h, o[ni], 0,0,0);
                o[ni] = __builtin_amdgcn_mfma_f32_16x16x32_bf16(pah[ks], v8l, o[ni], 0,0,0);
                o[ni] = __builtin_amdgcn_mfma_f32_16x16x32_bf16(pal[ks], v8h, o[ni], 0,0,0);
            }
        }
    }
    const size_t ob = (size_t)(b*T_ + qrow);
    #pragma unroll
    for (int ni=0;ni<4;++ni){
        const int col = h*64 + ni*16 + l16;
        #pragma unroll
        for (int r=0;r<4;++r)
            att[(ob + quad*4 + r)*D_ + col] = o[ni][r] / l_i[r];
    }
}

// ---- round-3 proven f32-in GEMM (A f32, Bt f32 [N,K], bias) for out-proj ----
__global__ __launch_bounds__(256) void gemm_bt(const float* __restrict__ A,
                                               const float* __restrict__ Bt,
                                               float* __restrict__ C,
                                               const float* __restrict__ bias,
                                               int M, int N, int K)
{
    __shared__ u16 Ash[128*32], Asl[128*32];
    __shared__ u16 Bsh[128*32], Bsl[128*32];
    const int n0 = blockIdx.x*128, m0 = blockIdx.y*128;
    const int t = threadIdx.x;
    const int w = t>>6, lane = t&63, quad = lane>>4, l16 = lane&15;
    const int wm = (w>>1)*64, wn = (w&1)*64;
    f32x4 acc[4][4];
    #pragma unroll
    for (int i=0;i<4;++i)
        #pragma unroll
        for (int j=0;j<4;++j) acc[i][j] = (f32x4){0.f,0.f,0.f,0.f};
    const int kT = K >> 5;
    for (int kt=0; kt<kT; ++kt){
        const int k0 = kt*32;
        #pragma unroll
        for (int i=0;i<4;++i){
            int ci = t + 256*i;
            int row = ci>>3, c4 = ci&7;
            float4 av = *(const float4*)(A  + (size_t)(m0+row)*K + k0 + c4*4);
            float4 bv = *(const float4*)(Bt + (size_t)(n0+row)*K + k0 + c4*4);
            U4 ah, al, bh, bl;
            split2(av.x, ah.s[0], al.s[0]); split2(av.y, ah.s[1], al.s[1]);
            split2(av.z, ah.s[2], al.s[2]); split2(av.w, ah.s[3], al.s[3]);
            split2(bv.x, bh.s[0], bl.s[0]); split2(bv.y, bh.s[1], bl.s[1]);
            split2(bv.z, bh.s[2], bl.s[2]); split2(bv.w, bh.s[3], bl.s[3]);
            *(uint2*)(Ash + row*32 + c4*4) = ah.v;
            *(uint2*)(Asl + row*32 + c4*4) = al.v;
            *(uint2*)(Bsh + row*32 + c4*4) = bh.v;
            *(uint2*)(Bsl + row*32 + c4*4) = bl.v;
        }
        __syncthreads();
        short8 afh[4], afl[4], bfh[4], bfl[4];
        #pragma unroll
        for (int mi=0;mi<4;++mi){
            afh[mi] = *(const short8*)(Ash + (wm+mi*16+l16)*32 + quad*8);
            afl[mi] = *(const short8*)(Asl + (wm+mi*16+l16)*32 + quad*8);
        }
        #pragma unroll
        for (int ni=0;ni<4;++ni){
            bfh[ni] = *(const short8*)(Bsh + (wn+ni*16+l16)*32 + quad*8);
            bfl[ni] = *(const short8*)(Bsl + (wn+ni*16+l16)*32 + quad*8);
        }
        #pragma unroll
        for (int mi=0;mi<4;++mi)
            #pragma unroll
            for (int ni=0;ni<4;++ni){
                acc[mi][ni] = __builtin_amdgcn_mfma_f32_16x16x32_bf16(afh[mi], bfh[ni], acc[mi][ni], 0,0,0);
                acc[mi][ni] = __builtin_amdgcn_mfma_f32_16x16x32_bf16(afh[mi], bfl[ni], acc[mi][ni], 0,0,0);
                acc[mi][ni] = __builtin_amdgcn_mfma_f32_16x16x32_bf16(afl[mi], bfh[ni], acc[mi][ni], 0,0,0);
            }
        __syncthreads();
    }
    #pragma unroll
    for (int ni=0;ni<4;++ni){
        const int col = n0 + wn + ni*16 + l16;
        const float bv = bias ? bias[col] : 0.f;
        #pragma unroll
        for (int mi=0;mi<4;++mi){
            const int row = m0 + wm + mi*16 + quad*4;
            #pragma unroll
            for (int r=0;r<4;++r)
                C[(size_t)(row+r)*N + col] = acc[mi][ni][r] + bv;
        }
    }
}

extern "C" void kernel_launch(void* const* d_in, const int* in_sizes, int n_in,
                              void* d_out, int out_size, void* d_ws, size_t ws_size,
                              hipStream_t stream)
{
    const float* x  = (const float*)d_in[0];
    const float* Wq = (const float*)d_in[1];
    const float* Wk = (const float*)d_in[2];
    const float* Wv = (const float*)d_in[3];
    const float* Wp = (const float*)d_in[4];
    const float* bp = (const float*)d_in[5];
    float* out = (float*)d_out;

    // workspace layout (134.2 MB total, proven footprint)
    float* q   = (float*)d_ws;                 // [BT][1024] f32
    u16*  kh   = (u16*)(q + (size_t)BT*D_);    // [BT][1024] u16
    u16*  kl   = kh + (size_t)BT*D_;
    u16*  vth  = kl + (size_t)BT*D_;           // [64bh][64e][2048t] u16
    u16*  vtl  = vth + (size_t)BT*D_;
    float* att = (float*)(vtl + (size_t)BT*D_);// [BT][1024] f32
    // Wt (split) aliases the att region: dead before attn writes att
    u16*  Wth  = (u16*)att;                    // [3072][1024] u16 (6.3 MB)
    u16*  Wtl  = Wth + (size_t)3072*D_;

    pack_w  <<<dim3(16,16,3), 256, 0, stream>>>(Wq, Wk, Wv, Wth, Wtl);
    gemm_qkv<<<dim3(24, BT/128), 256, 0, stream>>>(x, Wth, Wtl, q, kh, kl, vth, vtl);
    attn    <<<dim3(T_/128, B_*H_), 512, 0, stream>>>(q, kh, kl, vth, vtl, att);
    gemm_bt <<<dim3(8, BT/128), 256, 0, stream>>>(att, Wp, out, bp, BT, D_, D_);
}